// Round 3
// baseline (365.712 us; speedup 1.0000x reference)
//
#include <hip/hip_runtime.h>

#define NHEADS 16
#define DIM 128
#define MQ 1024
#define LK 1024

typedef short short8 __attribute__((ext_vector_type(8)));
typedef float f32x16 __attribute__((ext_vector_type(16)));

// (1/sqrt(128)) * log2(e): fold softmax scale + exp2-domain into Q conversion
#define QSCALE_L2E 0.12751722f

// pack two floats -> two bf16 (round-to-nearest-even), self-contained
__device__ __forceinline__ unsigned pk2(float a, float b) {
  unsigned ua = __builtin_bit_cast(unsigned, a);
  unsigned ub = __builtin_bit_cast(unsigned, b);
  ua += 0x7fffu + ((ua >> 16) & 1u);
  ub += 0x7fffu + ((ub >> 16) & 1u);
  return (ua >> 16) | (ub & 0xffff0000u);
}
__device__ __forceinline__ short8 ld8(const unsigned short* p) {
  return __builtin_bit_cast(short8, *(const uint4*)p);
}

// One block: 128 queries of one (b,h); 4 waves x 32 queries; K-tiles of 64.
// S^T = K*Q^T via mfma_32x32x16_bf16 (lane owns one query -> cheap online softmax),
// O^T = V^T * P^T. Pb OVERLAYS Ks (dead after S-compute) -> LDS 36864 B -> 4 blocks/CU.
__global__ __launch_bounds__(256, 4)
void SeqAttention_59579786330678_kernel(const float* __restrict__ Qg,
                                        const float* __restrict__ Kg,
                                        const float* __restrict__ Vg,
                                        const float* __restrict__ Sg,
                                        float* __restrict__ Og) {
  // LDS: region A (18432 B): Ks [64][136] bf16 (17408) then reused as Pb [4][32][72] bf16
  //      region B (18432 B): Vt [128][72] bf16
  // epilogue reuses all of SM as float Otr[4][32][68] (34816 B)
  __shared__ __align__(16) unsigned char SM[36864];
  unsigned short* Ks = (unsigned short*)SM;
  unsigned short* Pb = (unsigned short*)SM;           // overlays Ks
  unsigned short* Vt = (unsigned short*)(SM + 18432);

  const int tid = threadIdx.x;
  const int wid = tid >> 6;
  const int lane = tid & 63;
  const int lo = lane & 31;   // MFMA col -> this lane's query (within wave)
  const int hi = lane >> 5;   // MFMA k-half / row-offset bit

  // Head-stratified swizzle: co-resident blocks (stride-256) get heads {x,x+4,x+8,x+12}
  // bijection: bits[9:8]=q, bit[7], bits[6:4]=b, bits[3:0]=low4
  const int bi = blockIdx.x;
  const int q = bi >> 8;
  const int h = ((bi & 15) + (q << 2)) & 15;
  const int b = (bi >> 4) & 7;
  const int mt = (((bi >> 7) & 1) << 2) | q;
  const int bh = b * NHEADS + h;
  const int m0 = mt << 7;

  const float sv = Sg[h];
  // mask(n) = clamp((n - tval)/32, 0, 1); zero for n <= floor(tval) -> skip those tiles (exact)
  const float tval = 991.0f - sv * 1024.0f;
  int nf = (int)floorf(tval);
  nf = nf < 0 ? 0 : nf;
  const int tile0 = nf >> 6;

  // loop-invariant Q fragments (B-operand of K*Q^T), scale folded into bf16 convert
  short8 qf[8];
  {
    const float* qrow = Qg + ((size_t)bh * MQ + m0 + wid * 32 + lo) * DIM + hi * 8;
#pragma unroll
    for (int kc = 0; kc < 8; ++kc) {
      float4 x = *(const float4*)(qrow + kc * 16);
      float4 y = *(const float4*)(qrow + kc * 16 + 4);
      uint4 u;
      u.x = pk2(x.x * QSCALE_L2E, x.y * QSCALE_L2E);
      u.y = pk2(x.z * QSCALE_L2E, x.w * QSCALE_L2E);
      u.z = pk2(y.x * QSCALE_L2E, y.y * QSCALE_L2E);
      u.w = pk2(y.z * QSCALE_L2E, y.w * QSCALE_L2E);
      qf[kc] = __builtin_bit_cast(short8, u);
    }
  }

  f32x16 accO[4] = {};              // O^T accumulator: 4 d-blocks of 32
  float Mrun = -3.0e38f, lrun = 0.0f;
  const float hoff = (float)hi * 0.125f;   // 4*hi/32 row offset for mask

  const int vnp2 = (tid >> 3) * 2;  // V staging: key-pair base
  const int vdq = (tid & 7) * 4;    // V staging: d quad base
  const int kn = tid >> 4;          // K staging: row
  const int kc0 = (tid & 15) * 8;   // K staging: col base

  const float* Kbh = Kg + (size_t)bh * LK * DIM;
  const float* Vbh = Vg + (size_t)bh * LK * DIM;

  for (int it = tile0; it < 16; ++it) {
    const int n0 = it << 6;
    // ---- stage K tile: bf16, n-major, pad 136 ----
#pragma unroll
    for (int p = 0; p < 4; ++p) {
      const int n = kn + p * 16;
      const float* kp = Kbh + (size_t)(n0 + n) * DIM + kc0;
      float4 a = *(const float4*)kp;
      float4 bb = *(const float4*)(kp + 4);
      uint4 u;
      u.x = pk2(a.x, a.y); u.y = pk2(a.z, a.w);
      u.z = pk2(bb.x, bb.y); u.w = pk2(bb.z, bb.w);
      *(uint4*)&Ks[n * 136 + kc0] = u;
    }
    // ---- stage V tile transposed: Vt[d][n], key-pairs packed in one u32 write ----
#pragma unroll
    for (int p = 0; p < 4; ++p) {
      const int d0 = p * 32 + vdq;
      const float* vp = Vbh + (size_t)(n0 + vnp2) * DIM + d0;
      float4 a = *(const float4*)vp;
      float4 bb = *(const float4*)(vp + DIM);
      *(unsigned*)&Vt[(d0 + 0) * 72 + vnp2] = pk2(a.x, bb.x);
      *(unsigned*)&Vt[(d0 + 1) * 72 + vnp2] = pk2(a.y, bb.y);
      *(unsigned*)&Vt[(d0 + 2) * 72 + vnp2] = pk2(a.z, bb.z);
      *(unsigned*)&Vt[(d0 + 3) * 72 + vnp2] = pk2(a.w, bb.w);
    }
    __syncthreads();

    // ---- S^T = K * Q^T : rows n (0..63 in 2 blocks), cols m = lo ----
    f32x16 sa[2] = {};
#pragma unroll
    for (int kc = 0; kc < 8; ++kc) {
      short8 k0 = ld8(&Ks[lo * 136 + kc * 16 + hi * 8]);
      short8 k1 = ld8(&Ks[(32 + lo) * 136 + kc * 16 + hi * 8]);
      sa[0] = __builtin_amdgcn_mfma_f32_32x32x16_bf16(k0, qf[kc], sa[0], 0, 0, 0);
      sa[1] = __builtin_amdgcn_mfma_f32_32x32x16_bf16(k1, qf[kc], sa[1], 0, 0, 0);
    }

    __syncthreads();  // all waves done reading Ks -> region A reusable as Pb

    // ---- online softmax over n for query m = lo (in-lane + one xor-32 shuffle) ----
    float rm = -3.0e38f;
#pragma unroll
    for (int r = 0; r < 16; ++r) rm = fmaxf(rm, fmaxf(sa[0][r], sa[1][r]));
    rm = fmaxf(rm, __shfl_xor(rm, 32));
    const float Mn = fmaxf(Mrun, rm);
    const float alpha = __builtin_amdgcn_exp2f(Mrun - Mn);
    Mrun = Mn;

    const bool fullmask = ((float)n0 >= tval + 32.0f);  // whole tile has mask==1
    const float b0 = ((float)n0 - tval) * 0.03125f + hoff;
    unsigned short* pbrow = Pb + wid * (32 * 72) + lo * 72;
    float rs = 0.0f;
#pragma unroll
    for (int nb = 0; nb < 2; ++nb) {
#pragma unroll
      for (int g = 0; g < 4; ++g) {
        float pv0, pv1, pv2, pv3;
#pragma unroll
        for (int i = 0; i < 4; ++i) {
          float e = __builtin_amdgcn_exp2f(sa[nb][g * 4 + i] - Mn);
          if (!fullmask) {
            float mv = b0 + (float)(i + 8 * g + 32 * nb) * 0.03125f;
            mv = __builtin_amdgcn_fmed3f(mv, 0.0f, 1.0f);
            e *= mv;
          }
          rs += e;
          if (i == 0) pv0 = e; else if (i == 1) pv1 = e; else if (i == 2) pv2 = e; else pv3 = e;
        }
        uint2 w;
        w.x = pk2(pv0, pv1);
        w.y = pk2(pv2, pv3);
        // n = i + 8g + 4hi + 32nb, row = query m = lo  (P stored m-major for PV B-frags)
        *(uint2*)(pbrow + nb * 32 + g * 8 + hi * 4) = w;
      }
    }
    rs += __shfl_xor(rs, 32);
    lrun = lrun * alpha + rs;
#pragma unroll
    for (int db = 0; db < 4; ++db)
#pragma unroll
      for (int r = 0; r < 16; ++r) accO[db][r] *= alpha;

    // ---- O^T += V^T * P^T  (wave reads ONLY its own Pb slice -> no barrier needed) ----
#pragma unroll
    for (int pc = 0; pc < 4; ++pc) {
      short8 pf = ld8(&Pb[wid * (32 * 72) + lo * 72 + pc * 16 + hi * 8]);
#pragma unroll
      for (int db = 0; db < 4; ++db) {
        short8 vf = ld8(&Vt[(db * 32 + lo) * 72 + pc * 16 + hi * 8]);
        accO[db] = __builtin_amdgcn_mfma_f32_32x32x16_bf16(vf, pf, accO[db], 0, 0, 0);
      }
    }
    __syncthreads();  // protect A (Pb) and B (Vt) for next iteration's staging
  }

  // ---- epilogue: /l, transpose O^T -> O via LDS (two d-halves), coalesced stores ----
  const float invl = 1.0f / lrun;
  float* Otr = (float*)SM + wid * (32 * 68);
  const size_t obase = ((size_t)bh * MQ + m0 + wid * 32) * DIM;
#pragma unroll
  for (int hf = 0; hf < 2; ++hf) {
    __syncthreads();
#pragma unroll
    for (int db = 0; db < 2; ++db) {
      const int adb = hf * 2 + db;
#pragma unroll
      for (int r = 0; r < 16; ++r) {
        const int dl = db * 32 + (r & 3) + 8 * (r >> 2) + 4 * hi;
        Otr[lo * 68 + dl] = accO[adb][r] * invl;
      }
    }
    __syncthreads();
    const int mr = lane >> 1;
    const int c0 = (lane & 1) * 32;
    const float* src = Otr + mr * 68 + c0;
    float* dst = Og + obase + (size_t)mr * DIM + hf * 64 + c0;
#pragma unroll
    for (int i = 0; i < 8; ++i)
      *(float4*)(dst + i * 4) = *(const float4*)(src + i * 4);
  }
}

extern "C" void kernel_launch(void* const* d_in, const int* in_sizes, int n_in,
                              void* d_out, int out_size, void* d_ws, size_t ws_size,
                              hipStream_t stream) {
  const float* Q = (const float*)d_in[0];
  const float* K = (const float*)d_in[1];
  const float* V = (const float*)d_in[2];
  const float* S = (const float*)d_in[3];
  float* O = (float*)d_out;
  dim3 grid(1024);   // 128 bh x 8 m-tiles (head-stratified swizzle inside kernel)
  dim3 block(256);   // 4 waves x 32 queries each
  SeqAttention_59579786330678_kernel<<<grid, block, 0, stream>>>(Q, K, V, S, O);
}

// Round 4
// 294.336 us; speedup vs baseline: 1.2425x; 1.2425x over previous
//
#include <hip/hip_runtime.h>

#define NHEADS 16
#define DIM 128
#define MQ 1024
#define LK 1024

#define K_BYTES 17408          // 64 rows x 136 ushort
#define V_BYTES 18432          // 128 rows x 72 ushort
#define TILE_BYTES 35840       // K_BYTES + V_BYTES
#define WS_NEED ((size_t)128 * 16 * TILE_BYTES)   // 73,400,320 B

typedef short short8 __attribute__((ext_vector_type(8)));
typedef float f32x16 __attribute__((ext_vector_type(16)));

// (1/sqrt(128)) * log2(e): fold softmax scale + exp2-domain into Q conversion
#define QSCALE_L2E 0.12751722f

// pack two floats -> two bf16 (round-to-nearest-even), self-contained
__device__ __forceinline__ unsigned pk2(float a, float b) {
  unsigned ua = __builtin_bit_cast(unsigned, a);
  unsigned ub = __builtin_bit_cast(unsigned, b);
  ua += 0x7fffu + ((ua >> 16) & 1u);
  ub += 0x7fffu + ((ub >> 16) & 1u);
  return (ua >> 16) | (ub & 0xffff0000u);
}
__device__ __forceinline__ short8 ld8(const unsigned short* p) {
  return __builtin_bit_cast(short8, *(const uint4*)p);
}

typedef const __attribute__((address_space(1))) void gvoid_t;
typedef __attribute__((address_space(3))) void lvoid_t;
__device__ __forceinline__ void gl_lds16(const void* g, void* l) {
  __builtin_amdgcn_global_load_lds((gvoid_t*)g, (lvoid_t*)l, 16, 0, 0);
}

// ---------------- prep kernel: fp32 K/V -> padded bf16 K-tile + transposed V-tile in ws ----
__global__ __launch_bounds__(256)
void SeqAttention_prep_kernel(const float* __restrict__ Kg,
                              const float* __restrict__ Vg,
                              const float* __restrict__ Sg,
                              unsigned char* __restrict__ ws) {
  const int bid = blockIdx.x;           // 2048 = 128 bh x 16 tiles
  const int bh = bid >> 4;
  const int it = bid & 15;
  const float sv = Sg[bh & (NHEADS - 1)];
  const float tval = 991.0f - sv * 1024.0f;
  int nf = (int)floorf(tval);
  nf = nf < 0 ? 0 : nf;
  if (it < (nf >> 6)) return;           // tile fully masked for this head -> never read

  const int tid = threadIdx.x;
  const int n0 = it << 6;
  unsigned char* dst = ws + (size_t)bid * TILE_BYTES;

  // ---- K: direct convert, rows stride 136 ushort ----
  {
    const int kn = tid >> 4;
    const int kc0 = (tid & 15) * 8;
    const float* Kb = Kg + (size_t)bh * LK * DIM;
    unsigned short* dk = (unsigned short*)dst;
#pragma unroll
    for (int p = 0; p < 4; ++p) {
      const int n = kn + p * 16;
      const float* kp = Kb + (size_t)(n0 + n) * DIM + kc0;
      float4 a = *(const float4*)kp;
      float4 bb = *(const float4*)(kp + 4);
      uint4 u;
      u.x = pk2(a.x, a.y); u.y = pk2(a.z, a.w);
      u.z = pk2(bb.x, bb.y); u.w = pk2(bb.z, bb.w);
      *(uint4*)&dk[n * 136 + kc0] = u;
    }
  }

  // ---- V: transpose via LDS, rows stride 72 ushort ----
  __shared__ __align__(16) unsigned short Vt[128 * 72];
  {
    const int vnp2 = (tid >> 3) * 2;
    const int vdq = (tid & 7) * 4;
    const float* Vb = Vg + (size_t)bh * LK * DIM;
#pragma unroll
    for (int p = 0; p < 4; ++p) {
      const int d0 = p * 32 + vdq;
      const float* vp = Vb + (size_t)(n0 + vnp2) * DIM + d0;
      float4 a = *(const float4*)vp;
      float4 bb = *(const float4*)(vp + DIM);
      *(unsigned*)&Vt[(d0 + 0) * 72 + vnp2] = pk2(a.x, bb.x);
      *(unsigned*)&Vt[(d0 + 1) * 72 + vnp2] = pk2(a.y, bb.y);
      *(unsigned*)&Vt[(d0 + 2) * 72 + vnp2] = pk2(a.z, bb.z);
      *(unsigned*)&Vt[(d0 + 3) * 72 + vnp2] = pk2(a.w, bb.w);
    }
  }
  __syncthreads();
  {
    const int d = tid >> 3;
    const int ch = tid & 7;
#pragma unroll
    for (int p = 0; p < 4; ++p) {
      const int dd = d + p * 32;
      *(uint4*)(dst + K_BYTES + dd * 144 + ch * 16) = *(const uint4*)&Vt[dd * 72 + ch * 8];
    }
  }
}

// ---------------- main kernel (prepped ws): async LDS staging, no inline convert ----------
__global__ __launch_bounds__(256, 3)
void SeqAttention_59579786330678_kernel(const float* __restrict__ Qg,
                                        const unsigned char* __restrict__ ws,
                                        const float* __restrict__ Sg,
                                        float* __restrict__ Og) {
  // LDS: region A (18432 B): Ks [64][136] bf16 (17408) then reused as Pb [4][32][72] bf16
  //      region B (18432 B): Vt [128][72] bf16
  // epilogue reuses all of SM as float Otr[4][32][68] (34816 B)
  __shared__ __align__(16) unsigned char SM[36864];
  unsigned short* Ks = (unsigned short*)SM;
  unsigned short* Pb = (unsigned short*)SM;           // overlays Ks
  unsigned short* Vt = (unsigned short*)(SM + 18432);

  const int tid = threadIdx.x;
  const int wid = tid >> 6;
  const int lane = tid & 63;
  const int lo = lane & 31;   // MFMA col -> this lane's query (within wave)
  const int hi = lane >> 5;   // MFMA k-half / row-offset bit

  // Head-stratified swizzle: co-resident blocks (stride-256) get heads {x,x+4,x+8,x+12}
  const int bi = blockIdx.x;
  const int q = bi >> 8;
  const int h = ((bi & 15) + (q << 2)) & 15;
  const int b = (bi >> 4) & 7;
  const int mt = (((bi >> 7) & 1) << 2) | q;
  const int bh = b * NHEADS + h;
  const int m0 = mt << 7;

  const float sv = Sg[h];
  const float tval = 991.0f - sv * 1024.0f;
  int nf = (int)floorf(tval);
  nf = nf < 0 ? 0 : nf;
  const int tile0 = nf >> 6;

  // loop-invariant Q fragments (B-operand of K*Q^T), scale folded into bf16 convert
  short8 qf[8];
  {
    const float* qrow = Qg + ((size_t)bh * MQ + m0 + wid * 32 + lo) * DIM + hi * 8;
#pragma unroll
    for (int kc = 0; kc < 8; ++kc) {
      float4 x = *(const float4*)(qrow + kc * 16);
      float4 y = *(const float4*)(qrow + kc * 16 + 4);
      uint4 u;
      u.x = pk2(x.x * QSCALE_L2E, x.y * QSCALE_L2E);
      u.y = pk2(x.z * QSCALE_L2E, x.w * QSCALE_L2E);
      u.z = pk2(y.x * QSCALE_L2E, y.y * QSCALE_L2E);
      u.w = pk2(y.z * QSCALE_L2E, y.w * QSCALE_L2E);
      qf[kc] = __builtin_bit_cast(short8, u);
    }
  }

  f32x16 accO[4] = {};              // O^T accumulator: 4 d-blocks of 32
  float Mrun = -3.0e38f, lrun = 0.0f;
  const float hoff = (float)hi * 0.125f;   // 4*hi/32 row offset for mask

  const unsigned char* wsb = ws + (size_t)bh * 16 * TILE_BYTES;

  for (int it = tile0; it < 16; ++it) {
    const int n0 = it << 6;
    const unsigned char* src = wsb + (size_t)it * TILE_BYTES;
    // ---- async stage: 17 KB K-tile + 18 KB Vt-tile, 1KB chunks, width=16 ----
    for (int c = wid; c < 17; c += 4)
      gl_lds16(src + c * 1024 + lane * 16, SM + c * 1024);
    for (int c = wid; c < 18; c += 4)
      gl_lds16(src + K_BYTES + c * 1024 + lane * 16, SM + 18432 + c * 1024);
    __syncthreads();   // drains vmcnt (global_load_lds) before any reads

    // ---- S^T = K * Q^T : rows n (0..63 in 2 blocks), cols m = lo ----
    f32x16 sa[2] = {};
#pragma unroll
    for (int kc = 0; kc < 8; ++kc) {
      short8 k0 = ld8(&Ks[lo * 136 + kc * 16 + hi * 8]);
      short8 k1 = ld8(&Ks[(32 + lo) * 136 + kc * 16 + hi * 8]);
      sa[0] = __builtin_amdgcn_mfma_f32_32x32x16_bf16(k0, qf[kc], sa[0], 0, 0, 0);
      sa[1] = __builtin_amdgcn_mfma_f32_32x32x16_bf16(k1, qf[kc], sa[1], 0, 0, 0);
    }

    __syncthreads();  // all waves done reading Ks -> region A reusable as Pb

    // ---- online softmax over n for query m = lo ----
    float rm = -3.0e38f;
#pragma unroll
    for (int r = 0; r < 16; ++r) rm = fmaxf(rm, fmaxf(sa[0][r], sa[1][r]));
    rm = fmaxf(rm, __shfl_xor(rm, 32));
    const float Mn = fmaxf(Mrun, rm);
    const float alpha = __builtin_amdgcn_exp2f(Mrun - Mn);
    Mrun = Mn;

    const bool fullmask = ((float)n0 >= tval + 32.0f);  // whole tile has mask==1
    const float b0 = ((float)n0 - tval) * 0.03125f + hoff;
    unsigned short* pbrow = Pb + wid * (32 * 72) + lo * 72;
    float rs = 0.0f;
#pragma unroll
    for (int nb = 0; nb < 2; ++nb) {
#pragma unroll
      for (int g = 0; g < 4; ++g) {
        float pv0, pv1, pv2, pv3;
#pragma unroll
        for (int i = 0; i < 4; ++i) {
          float e = __builtin_amdgcn_exp2f(sa[nb][g * 4 + i] - Mn);
          if (!fullmask) {
            float mv = b0 + (float)(i + 8 * g + 32 * nb) * 0.03125f;
            mv = __builtin_amdgcn_fmed3f(mv, 0.0f, 1.0f);
            e *= mv;
          }
          rs += e;
          if (i == 0) pv0 = e; else if (i == 1) pv1 = e; else if (i == 2) pv2 = e; else pv3 = e;
        }
        uint2 w;
        w.x = pk2(pv0, pv1);
        w.y = pk2(pv2, pv3);
        // n = i + 8g + 4hi + 32nb, row = query m = lo  (P stored m-major for PV B-frags)
        *(uint2*)(pbrow + nb * 32 + g * 8 + hi * 4) = w;
      }
    }
    rs += __shfl_xor(rs, 32);
    lrun = lrun * alpha + rs;
#pragma unroll
    for (int db = 0; db < 4; ++db)
#pragma unroll
      for (int r = 0; r < 16; ++r) accO[db][r] *= alpha;

    // ---- O^T += V^T * P^T  (wave reads ONLY its own Pb slice -> no barrier needed) ----
#pragma unroll
    for (int pc = 0; pc < 4; ++pc) {
      short8 pf = ld8(&Pb[wid * (32 * 72) + lo * 72 + pc * 16 + hi * 8]);
#pragma unroll
      for (int db = 0; db < 4; ++db) {
        short8 vf = ld8(&Vt[(db * 32 + lo) * 72 + pc * 16 + hi * 8]);
        accO[db] = __builtin_amdgcn_mfma_f32_32x32x16_bf16(vf, pf, accO[db], 0, 0, 0);
      }
    }
    __syncthreads();  // protect A (Pb) and B (Vt) for next iteration's staging
  }

  // ---- epilogue: /l, transpose O^T -> O via LDS (two d-halves), coalesced stores ----
  const float invl = 1.0f / lrun;
  float* Otr = (float*)SM + wid * (32 * 68);
  const size_t obase = ((size_t)bh * MQ + m0 + wid * 32) * DIM;
#pragma unroll
  for (int hf = 0; hf < 2; ++hf) {
    __syncthreads();
#pragma unroll
    for (int db = 0; db < 2; ++db) {
      const int adb = hf * 2 + db;
#pragma unroll
      for (int r = 0; r < 16; ++r) {
        const int dl = db * 32 + (r & 3) + 8 * (r >> 2) + 4 * hi;
        Otr[lo * 68 + dl] = accO[adb][r] * invl;
      }
    }
    __syncthreads();
    const int mr = lane >> 1;
    const int c0 = (lane & 1) * 32;
    const float* src2 = Otr + mr * 68 + c0;
    float* dst = Og + obase + (size_t)mr * DIM + hf * 64 + c0;
#pragma unroll
    for (int i = 0; i < 8; ++i)
      *(float4*)(dst + i * 4) = *(const float4*)(src2 + i * 4);
  }
}

// ---------------- fallback (small ws): inline-convert version, (256,3) ----------
__global__ __launch_bounds__(256, 3)
void SeqAttention_inline_kernel(const float* __restrict__ Qg,
                                const float* __restrict__ Kg,
                                const float* __restrict__ Vg,
                                const float* __restrict__ Sg,
                                float* __restrict__ Og) {
  __shared__ __align__(16) unsigned char SM[36864];
  unsigned short* Ks = (unsigned short*)SM;
  unsigned short* Pb = (unsigned short*)SM;
  unsigned short* Vt = (unsigned short*)(SM + 18432);

  const int tid = threadIdx.x;
  const int wid = tid >> 6;
  const int lane = tid & 63;
  const int lo = lane & 31;
  const int hi = lane >> 5;

  const int bi = blockIdx.x;
  const int q = bi >> 8;
  const int h = ((bi & 15) + (q << 2)) & 15;
  const int b = (bi >> 4) & 7;
  const int mt = (((bi >> 7) & 1) << 2) | q;
  const int bh = b * NHEADS + h;
  const int m0 = mt << 7;

  const float sv = Sg[h];
  const float tval = 991.0f - sv * 1024.0f;
  int nf = (int)floorf(tval);
  nf = nf < 0 ? 0 : nf;
  const int tile0 = nf >> 6;

  short8 qf[8];
  {
    const float* qrow = Qg + ((size_t)bh * MQ + m0 + wid * 32 + lo) * DIM + hi * 8;
#pragma unroll
    for (int kc = 0; kc < 8; ++kc) {
      float4 x = *(const float4*)(qrow + kc * 16);
      float4 y = *(const float4*)(qrow + kc * 16 + 4);
      uint4 u;
      u.x = pk2(x.x * QSCALE_L2E, x.y * QSCALE_L2E);
      u.y = pk2(x.z * QSCALE_L2E, x.w * QSCALE_L2E);
      u.z = pk2(y.x * QSCALE_L2E, y.y * QSCALE_L2E);
      u.w = pk2(y.z * QSCALE_L2E, y.w * QSCALE_L2E);
      qf[kc] = __builtin_bit_cast(short8, u);
    }
  }

  f32x16 accO[4] = {};
  float Mrun = -3.0e38f, lrun = 0.0f;
  const float hoff = (float)hi * 0.125f;

  const int vnp2 = (tid >> 3) * 2;
  const int vdq = (tid & 7) * 4;
  const int kn = tid >> 4;
  const int kc0 = (tid & 15) * 8;

  const float* Kbh = Kg + (size_t)bh * LK * DIM;
  const float* Vbh = Vg + (size_t)bh * LK * DIM;

  for (int it = tile0; it < 16; ++it) {
    const int n0 = it << 6;
#pragma unroll
    for (int p = 0; p < 4; ++p) {
      const int n = kn + p * 16;
      const float* kp = Kbh + (size_t)(n0 + n) * DIM + kc0;
      float4 a = *(const float4*)kp;
      float4 bb = *(const float4*)(kp + 4);
      uint4 u;
      u.x = pk2(a.x, a.y); u.y = pk2(a.z, a.w);
      u.z = pk2(bb.x, bb.y); u.w = pk2(bb.z, bb.w);
      *(uint4*)&Ks[n * 136 + kc0] = u;
    }
#pragma unroll
    for (int p = 0; p < 4; ++p) {
      const int d0 = p * 32 + vdq;
      const float* vp = Vbh + (size_t)(n0 + vnp2) * DIM + d0;
      float4 a = *(const float4*)vp;
      float4 bb = *(const float4*)(vp + DIM);
      *(unsigned*)&Vt[(d0 + 0) * 72 + vnp2] = pk2(a.x, bb.x);
      *(unsigned*)&Vt[(d0 + 1) * 72 + vnp2] = pk2(a.y, bb.y);
      *(unsigned*)&Vt[(d0 + 2) * 72 + vnp2] = pk2(a.z, bb.z);
      *(unsigned*)&Vt[(d0 + 3) * 72 + vnp2] = pk2(a.w, bb.w);
    }
    __syncthreads();

    f32x16 sa[2] = {};
#pragma unroll
    for (int kc = 0; kc < 8; ++kc) {
      short8 k0 = ld8(&Ks[lo * 136 + kc * 16 + hi * 8]);
      short8 k1 = ld8(&Ks[(32 + lo) * 136 + kc * 16 + hi * 8]);
      sa[0] = __builtin_amdgcn_mfma_f32_32x32x16_bf16(k0, qf[kc], sa[0], 0, 0, 0);
      sa[1] = __builtin_amdgcn_mfma_f32_32x32x16_bf16(k1, qf[kc], sa[1], 0, 0, 0);
    }
    __syncthreads();

    float rm = -3.0e38f;
#pragma unroll
    for (int r = 0; r < 16; ++r) rm = fmaxf(rm, fmaxf(sa[0][r], sa[1][r]));
    rm = fmaxf(rm, __shfl_xor(rm, 32));
    const float Mn = fmaxf(Mrun, rm);
    const float alpha = __builtin_amdgcn_exp2f(Mrun - Mn);
    Mrun = Mn;

    const bool fullmask = ((float)n0 >= tval + 32.0f);
    const float b0 = ((float)n0 - tval) * 0.03125f + hoff;
    unsigned short* pbrow = Pb + wid * (32 * 72) + lo * 72;
    float rs = 0.0f;
#pragma unroll
    for (int nb = 0; nb < 2; ++nb) {
#pragma unroll
      for (int g = 0; g < 4; ++g) {
        float pv0, pv1, pv2, pv3;
#pragma unroll
        for (int i = 0; i < 4; ++i) {
          float e = __builtin_amdgcn_exp2f(sa[nb][g * 4 + i] - Mn);
          if (!fullmask) {
            float mv = b0 + (float)(i + 8 * g + 32 * nb) * 0.03125f;
            mv = __builtin_amdgcn_fmed3f(mv, 0.0f, 1.0f);
            e *= mv;
          }
          rs += e;
          if (i == 0) pv0 = e; else if (i == 1) pv1 = e; else if (i == 2) pv2 = e; else pv3 = e;
        }
        uint2 w;
        w.x = pk2(pv0, pv1);
        w.y = pk2(pv2, pv3);
        *(uint2*)(pbrow + nb * 32 + g * 8 + hi * 4) = w;
      }
    }
    rs += __shfl_xor(rs, 32);
    lrun = lrun * alpha + rs;
#pragma unroll
    for (int db = 0; db < 4; ++db)
#pragma unroll
      for (int r = 0; r < 16; ++r) accO[db][r] *= alpha;

#pragma unroll
    for (int pc = 0; pc < 4; ++pc) {
      short8 pf = ld8(&Pb[wid * (32 * 72) + lo * 72 + pc * 16 + hi * 8]);
#pragma unroll
      for (int db = 0; db < 4; ++db) {
        short8 vf = ld8(&Vt[(db * 32 + lo) * 72 + pc * 16 + hi * 8]);
        accO[db] = __builtin_amdgcn_mfma_f32_32x32x16_bf16(vf, pf, accO[db], 0, 0, 0);
      }
    }
    __syncthreads();
  }

  const float invl = 1.0f / lrun;
  float* Otr = (float*)SM + wid * (32 * 68);
  const size_t obase = ((size_t)bh * MQ + m0 + wid * 32) * DIM;
#pragma unroll
  for (int hf = 0; hf < 2; ++hf) {
    __syncthreads();
#pragma unroll
    for (int db = 0; db < 2; ++db) {
      const int adb = hf * 2 + db;
#pragma unroll
      for (int r = 0; r < 16; ++r) {
        const int dl = db * 32 + (r & 3) + 8 * (r >> 2) + 4 * hi;
        Otr[lo * 68 + dl] = accO[adb][r] * invl;
      }
    }
    __syncthreads();
    const int mr = lane >> 1;
    const int c0 = (lane & 1) * 32;
    const float* src2 = Otr + mr * 68 + c0;
    float* dst = Og + obase + (size_t)mr * DIM + hf * 64 + c0;
#pragma unroll
    for (int i = 0; i < 8; ++i)
      *(float4*)(dst + i * 4) = *(const float4*)(src2 + i * 4);
  }
}

extern "C" void kernel_launch(void* const* d_in, const int* in_sizes, int n_in,
                              void* d_out, int out_size, void* d_ws, size_t ws_size,
                              hipStream_t stream) {
  const float* Q = (const float*)d_in[0];
  const float* K = (const float*)d_in[1];
  const float* V = (const float*)d_in[2];
  const float* S = (const float*)d_in[3];
  float* O = (float*)d_out;
  if (ws_size >= WS_NEED) {
    SeqAttention_prep_kernel<<<2048, 256, 0, stream>>>(K, V, S, (unsigned char*)d_ws);
    SeqAttention_59579786330678_kernel<<<1024, 256, 0, stream>>>(
        Q, (const unsigned char*)d_ws, S, O);
  } else {
    SeqAttention_inline_kernel<<<1024, 256, 0, stream>>>(Q, K, V, S, O);
  }
}